// Round 15
// baseline (357.069 us; speedup 1.0000x reference)
//
#include <hip/hip_runtime.h>
#include <math.h>

// Problem constants
#define CCH 64
#define HH  128
#define WW  128
#define NB  4
#define NPIX (NB*HH*WW)   // 65536
#define NWG  (NPIX/64)    // 1024 blocks for the pixel kernels

// XCD-aware block swizzle (T1): each XCD gets a contiguous 64-row slice.
__device__ __forceinline__ int swz_block(int bid) {
    return (bid & 7) * (NWG >> 3) + (bid >> 3);
}

// ---------------------------------------------------------------------------
// Kernel 1: prep (first 144 blocks) + fused 4-layer MLP -> feat2 (NHWC) and
// featN (NCHW aliased into d_out; dead until dcn's final write).
// ---------------------------------------------------------------------------
__global__ __launch_bounds__(256) void mlp_kernel(
    const float* __restrict__ ev, const float* __restrict__ im,
    const float* __restrict__ w0, const float* __restrict__ b0,
    const float* __restrict__ w1, const float* __restrict__ b1,
    const float* __restrict__ w2, const float* __restrict__ b2,
    const float* __restrict__ w3, const float* __restrict__ b3,
    const float* __restrict__ off_w, const float* __restrict__ dcn_w,
    float* __restrict__ offT, float* __restrict__ dcnT,
    float* __restrict__ feat2, float* __restrict__ featN)
{
    __shared__ float xA[64 * 65];   // [ch][px], padded
    __shared__ float xB[64 * 65];
    int tid  = threadIdx.x;

    // folded prep: transpose conv weights (blocks 0..143)
    if (blockIdx.x < 144) {
        int idx = blockIdx.x * 256 + tid;
        if (idx < 576 * 28) {
            int rc = idx / 28;       // ic*9+kk
            int o  = idx % 28;
            offT[rc * 28 + o] = (o < 27) ? off_w[o * 576 + rc] : 0.0f;
        }
        if (idx < 36864) {
            int o    = idx & 63;
            int rest = idx >> 6;
            int ic   = rest & 63;
            int k    = rest >> 6;
            dcnT[(k * 64 + ic) * 64 + o] = dcn_w[o * 576 + ic * 9 + k];
        }
    }

    int cg   = __builtin_amdgcn_readfirstlane(tid >> 6);
    int lane = tid & 63;
    int sw   = swz_block(blockIdx.x);
    int p = sw * 64 + lane;
    int b = p >> 14;
    int q = p & 16383;
    int h = q >> 7;
    int w = q & 127;
    int c0 = cg * 16;

    float acc[16];
#pragma unroll
    for (int j = 0; j < 16; ++j) acc[j] = b0[c0 + j];

    const float* evb = ev + ((b * 64) * 64 + (h >> 1)) * 64 + (w >> 1);
    for (int i = 0; i < 64; ++i) {
        float v = evb[i * 4096];
        const float* wr = w0 + i * 64 + c0;
#pragma unroll
        for (int j = 0; j < 16; ++j) acc[j] = fmaf(v, wr[j], acc[j]);
    }
    const float* imb = im + ((b * 64) * 128 + h) * 128 + w;
    for (int i = 0; i < 64; ++i) {
        float v = imb[i * 16384];
        const float* wr = w0 + (64 + i) * 64 + c0;
#pragma unroll
        for (int j = 0; j < 16; ++j) acc[j] = fmaf(v, wr[j], acc[j]);
    }
    {
        float rely = (h & 1) ? 0.5f : -0.5f;
        float relx = (w & 1) ? 0.5f : -0.5f;
        const float* wr = w0 + 128 * 64 + c0;
#pragma unroll
        for (int j = 0; j < 16; ++j) acc[j] = fmaf(rely, wr[j], acc[j]);
#pragma unroll
        for (int j = 0; j < 16; ++j) acc[j] = fmaf(relx, wr[64 + j], acc[j]);
#pragma unroll
        for (int j = 0; j < 16; ++j) acc[j] += wr[128 + j] + wr[192 + j];
    }
#pragma unroll
    for (int j = 0; j < 16; ++j) xA[(c0 + j) * 65 + lane] = fmaxf(acc[j], 0.0f);
    __syncthreads();

#pragma unroll
    for (int j = 0; j < 16; ++j) acc[j] = b1[c0 + j];
    for (int i = 0; i < 64; ++i) {
        float v = xA[i * 65 + lane];
        const float* wr = w1 + i * 64 + c0;
#pragma unroll
        for (int j = 0; j < 16; ++j) acc[j] = fmaf(v, wr[j], acc[j]);
    }
#pragma unroll
    for (int j = 0; j < 16; ++j) xB[(c0 + j) * 65 + lane] = fmaxf(acc[j], 0.0f);
    __syncthreads();

#pragma unroll
    for (int j = 0; j < 16; ++j) acc[j] = b2[c0 + j];
    for (int i = 0; i < 64; ++i) {
        float v = xB[i * 65 + lane];
        const float* wr = w2 + i * 64 + c0;
#pragma unroll
        for (int j = 0; j < 16; ++j) acc[j] = fmaf(v, wr[j], acc[j]);
    }
#pragma unroll
    for (int j = 0; j < 16; ++j) xA[(c0 + j) * 65 + lane] = fmaxf(acc[j], 0.0f);
    __syncthreads();

#pragma unroll
    for (int j = 0; j < 16; ++j) acc[j] = b3[c0 + j];
    for (int i = 0; i < 64; ++i) {
        float v = xA[i * 65 + lane];
        const float* wr = w3 + i * 64 + c0;
#pragma unroll
        for (int j = 0; j < 16; ++j) acc[j] = fmaf(v, wr[j], acc[j]);
    }

    // NCHW store (coalesced: lanes = consecutive px)
    float* fbN = featN + (b * 64 + c0) * 16384 + q;
#pragma unroll
    for (int j = 0; j < 16; ++j) fbN[j * 16384] = acc[j];

    // NHWC store via padded-LDS transpose (coalesced float4)
#pragma unroll
    for (int j = 0; j < 16; ++j) xB[(c0 + j) * 65 + lane] = acc[j];
    __syncthreads();
    {
        int q0 = (sw * 64) & 16383;
        float* fb = feat2 + ((size_t)b * 16384 + q0) * 64;
        int ch0 = (tid & 15) * 4;
#pragma unroll
        for (int r = 0; r < 4; ++r) {
            int px = (tid >> 4) + r * 16;
            float4 v = make_float4(xB[(ch0 + 0) * 65 + px],
                                   xB[(ch0 + 1) * 65 + px],
                                   xB[(ch0 + 2) * 65 + px],
                                   xB[(ch0 + 3) * 65 + px]);
            ((float4*)fb)[tid + r * 256] = v;
        }
    }
}

// ---------------------------------------------------------------------------
// Kernel 2: 3x3 offset conv -> raw 27-ch oo.  NCHW reads (featN in d_out).
// ---------------------------------------------------------------------------
__global__ __launch_bounds__(256) void off_kernel(
    const float* __restrict__ featN, const float* __restrict__ offT,
    const float* __restrict__ off_b,
    float* __restrict__ oo)
{
    __shared__ float po[4 * 27 * 64];   // [wave][o][px]
    int tid  = threadIdx.x;
    int wv   = __builtin_amdgcn_readfirstlane(tid >> 6);
    int lane = tid & 63;
    int p = swz_block(blockIdx.x) * 64 + lane;
    int b = p >> 14;
    int q = p & 16383;
    int h = q >> 7;
    int w = q & 127;
    int c0 = wv * 16;

    float acc[27];
#pragma unroll
    for (int o = 0; o < 27; ++o) acc[o] = 0.0f;

    const float* fb = featN + (b * 64 + c0) * 16384;
    for (int i = 0; i < 16; ++i) {
        const float* f = fb + i * 16384;
        float v[9];
#pragma unroll
        for (int ky = 0; ky < 3; ++ky)
#pragma unroll
            for (int kx = 0; kx < 3; ++kx) {
                int y = h + ky - 1, x = w + kx - 1;
                bool ok = (y >= 0) && (y < 128) && (x >= 0) && (x < 128);
                v[ky * 3 + kx] = ok ? f[y * 128 + x] : 0.0f;
            }
#pragma unroll
        for (int kk = 0; kk < 9; ++kk) {
            const float* wr = offT + ((c0 + i) * 9 + kk) * 28;
#pragma unroll
            for (int o = 0; o < 27; ++o) acc[o] = fmaf(v[kk], wr[o], acc[o]);
        }
    }

#pragma unroll
    for (int o = 0; o < 27; ++o) po[(wv * 27 + o) * 64 + lane] = acc[o];
    __syncthreads();

#pragma unroll
    for (int j = 0; j < 7; ++j) {
        int o = wv + 4 * j;
        if (o < 27) {
            float s = off_b[o]
                    + po[o * 64 + lane] + po[(27 + o) * 64 + lane]
                    + po[(54 + o) * 64 + lane] + po[(81 + o) * 64 + lane];
            oo[((b * 27 + o) << 14) + q] = s;
        }
    }
}

// ---------------------------------------------------------------------------
// Kernel 3: transform + deformable sampling + einsum + bias.
// r14 structure with LDS traffic halved:
//  - sample LDS paired as float2 [pair][px]: writes 8 x b64, reads b64
//  - own 16-ic slice forwarded in registers across the barrier (own[16]),
//    only the 48 foreign ic read from LDS (24 x ds_read_b64 per k)
// FMA body keeps the proven scalar-sample x SGPR-weight-row pattern.
// ---------------------------------------------------------------------------
__device__ __forceinline__ void dcn_transform_r(
    float oy, float ox, float mlraw, int k, int h, int w,
    float& W00, float& W01, float& W10, float& W11,
    int& i00, int& i01, int& i10, int& i11)
{
    float ml = 1.0f / (1.0f + expf(-mlraw));
    float py = (float)(h + k / 3 - 1) + oy;
    float px = (float)(w + k % 3 - 1) + ox;

    float y0f = floorf(py), x0f = floorf(px);
    float ly = py - y0f, lx = px - x0f;
    int y0 = (int)y0f, x0 = (int)x0f;

    bool vy0 = (y0f >= 0.0f)        && (y0f <= 127.0f);
    bool vy1 = (y0f + 1.0f >= 0.0f) && (y0f + 1.0f <= 127.0f);
    bool vx0 = (x0f >= 0.0f)        && (x0f <= 127.0f);
    bool vx1 = (x0f + 1.0f >= 0.0f) && (x0f + 1.0f <= 127.0f);

    int yc0 = min(max(y0, 0), 127),     yc1 = min(max(y0 + 1, 0), 127);
    int xc0 = min(max(x0, 0), 127),     xc1 = min(max(x0 + 1, 0), 127);

    W00 = (1.0f - ly) * (1.0f - lx) * ml * ((vy0 && vx0) ? 1.0f : 0.0f);
    W01 = (1.0f - ly) * lx          * ml * ((vy0 && vx1) ? 1.0f : 0.0f);
    W10 = ly * (1.0f - lx)          * ml * ((vy1 && vx0) ? 1.0f : 0.0f);
    W11 = ly * lx                   * ml * ((vy1 && vx1) ? 1.0f : 0.0f);

    i00 = yc0 * 128 + xc0; i01 = yc0 * 128 + xc1;
    i10 = yc1 * 128 + xc0; i11 = yc1 * 128 + xc1;
}

__global__ __launch_bounds__(256) void dcn_kernel(
    const float* __restrict__ feat2,
    const float* __restrict__ oo,
    const float* __restrict__ dcnT, const float* __restrict__ dcn_b,
    float* __restrict__ out)
{
    __shared__ float2 sA2[32 * 64];   // [pair][px], 16 KB
    __shared__ float2 sB2[32 * 64];
    int tid  = threadIdx.x;
    int wv   = __builtin_amdgcn_readfirstlane(tid >> 6);
    int lane = tid & 63;
    int p = swz_block(blockIdx.x) * 64 + lane;
    int b = p >> 14;
    int q = p & 16383;
    int h = q >> 7;
    int w = q & 127;
    int c0 = wv * 16;        // this wave's ic slice AND o slice
    int pb0 = wv * 8;        // this wave's pair base

    float acc[16];
#pragma unroll
    for (int j = 0; j < 16; ++j) acc[j] = dcn_b[c0 + j];

    float own[16];           // this wave's blended samples (own lane's px)

    const float* fb2 = feat2 + (b * 16384) * 64 + c0;   // wave's 16-ic slice
    const float* oob = oo + ((b * 27) << 14) + q;

    // ---- prologue: k=0 transform+gather into sA2 + own[]; prefetch k=1 oo --
    {
        float oy = oob[0];
        float ox = oob[1 << 14];
        float om = oob[18 << 14];
        float W00, W01, W10, W11; int i00, i01, i10, i11;
        dcn_transform_r(oy, ox, om, 0, h, w, W00, W01, W10, W11, i00, i01, i10, i11);
        const float4* p00 = (const float4*)(fb2 + i00 * 64);
        const float4* p01 = (const float4*)(fb2 + i01 * 64);
        const float4* p10 = (const float4*)(fb2 + i10 * 64);
        const float4* p11 = (const float4*)(fb2 + i11 * 64);
#pragma unroll
        for (int g = 0; g < 4; ++g) {
            float4 a = p00[g], bb = p01[g], c = p10[g], d = p11[g];
            own[4 * g + 0] = W00 * a.x + W01 * bb.x + W10 * c.x + W11 * d.x;
            own[4 * g + 1] = W00 * a.y + W01 * bb.y + W10 * c.y + W11 * d.y;
            own[4 * g + 2] = W00 * a.z + W01 * bb.z + W10 * c.z + W11 * d.z;
            own[4 * g + 3] = W00 * a.w + W01 * bb.w + W10 * c.w + W11 * d.w;
            sA2[(pb0 + 2 * g) * 64 + lane]     = make_float2(own[4 * g + 0], own[4 * g + 1]);
            sA2[(pb0 + 2 * g + 1) * 64 + lane] = make_float2(own[4 * g + 2], own[4 * g + 3]);
        }
    }
    float oyN = oob[2 << 14];
    float oxN = oob[3 << 14];
    float omN = oob[19 << 14];
    __syncthreads();

    float2* cur = sA2;
    float2* nxt = sB2;

    for (int k = 0; k < 9; ++k) {
        bool pre = (k < 8);
        float W00, W01, W10, W11; int i00, i01, i10, i11;
        float4 a0, a1, b0, b1, c0v, c1v, d0, d1;
        const float4 *p00 = nullptr, *p01 = nullptr, *p10 = nullptr, *p11 = nullptr;

        if (pre) {
            dcn_transform_r(oyN, oxN, omN, k + 1, h, w,
                            W00, W01, W10, W11, i00, i01, i10, i11);
            if (k < 7) {
                oyN = oob[(2 * (k + 2)) << 14];
                oxN = oob[(2 * (k + 2) + 1) << 14];
                omN = oob[(18 + (k + 2)) << 14];
            }
            p00 = (const float4*)(fb2 + i00 * 64);
            p01 = (const float4*)(fb2 + i01 * 64);
            p10 = (const float4*)(fb2 + i10 * 64);
            p11 = (const float4*)(fb2 + i11 * 64);
            a0 = p00[0]; a1 = p00[1];
            b0 = p01[0]; b1 = p01[1];
            c0v = p10[0]; c1v = p10[1];
            d0 = p11[0]; d1 = p11[1];
        }

        const float* wk = dcnT + (k * 64) * 64 + c0;

        // FMA phase A: own 16 ic from registers (no LDS)
#pragma unroll
        for (int i = 0; i < 16; ++i) {
            float s = own[i];
            const float* wr = wk + (c0 + i) * 64;
#pragma unroll
            for (int j = 0; j < 16; ++j) acc[j] = fmaf(s, wr[j], acc[j]);
        }

        if (pre) {
            // blend batch 0 -> own[0..7] (for k+1) + LDS pairs
            own[0] = W00 * a0.x + W01 * b0.x + W10 * c0v.x + W11 * d0.x;
            own[1] = W00 * a0.y + W01 * b0.y + W10 * c0v.y + W11 * d0.y;
            own[2] = W00 * a0.z + W01 * b0.z + W10 * c0v.z + W11 * d0.z;
            own[3] = W00 * a0.w + W01 * b0.w + W10 * c0v.w + W11 * d0.w;
            own[4] = W00 * a1.x + W01 * b1.x + W10 * c1v.x + W11 * d1.x;
            own[5] = W00 * a1.y + W01 * b1.y + W10 * c1v.y + W11 * d1.y;
            own[6] = W00 * a1.z + W01 * b1.z + W10 * c1v.z + W11 * d1.z;
            own[7] = W00 * a1.w + W01 * b1.w + W10 * c1v.w + W11 * d1.w;
            nxt[(pb0 + 0) * 64 + lane] = make_float2(own[0], own[1]);
            nxt[(pb0 + 1) * 64 + lane] = make_float2(own[2], own[3]);
            nxt[(pb0 + 2) * 64 + lane] = make_float2(own[4], own[5]);
            nxt[(pb0 + 3) * 64 + lane] = make_float2(own[6], own[7]);
            a0 = p00[2]; a1 = p00[3];
            b0 = p01[2]; b1 = p01[3];
            c0v = p10[2]; c1v = p10[3];
            d0 = p11[2]; d1 = p11[3];
        }

        // FMA phase B: foreign slices +1, +2 (16 pairs via ds_read_b64)
#pragma unroll
        for (int ws = 1; ws <= 2; ++ws) {
            int fw = (wv + ws) & 3;
            int pb = fw * 8;
            const float* wf = wk + (fw * 16) * 64;
#pragma unroll
            for (int g = 0; g < 8; ++g) {
                float2 sv = cur[(pb + g) * 64 + lane];
                const float* wr = wf + (2 * g) * 64;
#pragma unroll
                for (int j = 0; j < 16; ++j) acc[j] = fmaf(sv.x, wr[j], acc[j]);
#pragma unroll
                for (int j = 0; j < 16; ++j) acc[j] = fmaf(sv.y, wr[64 + j], acc[j]);
            }
        }

        if (pre) {
            // blend batch 1 -> own[8..15] + LDS pairs
            own[8]  = W00 * a0.x + W01 * b0.x + W10 * c0v.x + W11 * d0.x;
            own[9]  = W00 * a0.y + W01 * b0.y + W10 * c0v.y + W11 * d0.y;
            own[10] = W00 * a0.z + W01 * b0.z + W10 * c0v.z + W11 * d0.z;
            own[11] = W00 * a0.w + W01 * b0.w + W10 * c0v.w + W11 * d0.w;
            own[12] = W00 * a1.x + W01 * b1.x + W10 * c1v.x + W11 * d1.x;
            own[13] = W00 * a1.y + W01 * b1.y + W10 * c1v.y + W11 * d1.y;
            own[14] = W00 * a1.z + W01 * b1.z + W10 * c1v.z + W11 * d1.z;
            own[15] = W00 * a1.w + W01 * b1.w + W10 * c1v.w + W11 * d1.w;
            nxt[(pb0 + 4) * 64 + lane] = make_float2(own[8],  own[9]);
            nxt[(pb0 + 5) * 64 + lane] = make_float2(own[10], own[11]);
            nxt[(pb0 + 6) * 64 + lane] = make_float2(own[12], own[13]);
            nxt[(pb0 + 7) * 64 + lane] = make_float2(own[14], own[15]);
        }

        // FMA phase C: foreign slice +3 (8 pairs)
        {
            int fw = (wv + 3) & 3;
            int pb = fw * 8;
            const float* wf = wk + (fw * 16) * 64;
#pragma unroll
            for (int g = 0; g < 8; ++g) {
                float2 sv = cur[(pb + g) * 64 + lane];
                const float* wr = wf + (2 * g) * 64;
#pragma unroll
                for (int j = 0; j < 16; ++j) acc[j] = fmaf(sv.x, wr[j], acc[j]);
#pragma unroll
                for (int j = 0; j < 16; ++j) acc[j] = fmaf(sv.y, wr[64 + j], acc[j]);
            }
        }

        __syncthreads();
        float2* t = cur; cur = nxt; nxt = t;
    }

    float* ob = out + (b * 64 + c0) * 16384 + q;
#pragma unroll
    for (int j = 0; j < 16; ++j) ob[j * 16384] = acc[j];
}

// ---------------------------------------------------------------------------
extern "C" void kernel_launch(void* const* d_in, const int* in_sizes, int n_in,
                              void* d_out, int out_size, void* d_ws, size_t ws_size,
                              hipStream_t stream)
{
    const float* ev    = (const float*)d_in[0];
    const float* im    = (const float*)d_in[1];
    const float* w0    = (const float*)d_in[2];
    const float* b0    = (const float*)d_in[3];
    const float* w1    = (const float*)d_in[4];
    const float* b1    = (const float*)d_in[5];
    const float* w2    = (const float*)d_in[6];
    const float* b2    = (const float*)d_in[7];
    const float* w3    = (const float*)d_in[8];
    const float* b3    = (const float*)d_in[9];
    const float* off_w = (const float*)d_in[10];
    const float* off_b = (const float*)d_in[11];
    const float* dcn_w = (const float*)d_in[12];
    const float* dcn_b = (const float*)d_in[13];
    float* out = (float*)d_out;

    char* ws = (char*)d_ws;
    float* feat2 = (float*)(ws);                       // 16,777,216 B (NHWC)
    float* oo    = (float*)(ws + 16777216);            //  7,077,888 B
    float* offT  = (float*)(ws + 23855104);            //     64,512 B
    float* dcnT  = (float*)(ws + 23920640);            //    147,456 B
    float* featN = out;   // NCHW copy aliased into d_out (dead before dcn's write)

    mlp_kernel<<<NWG, 256, 0, stream>>>(ev, im, w0, b0, w1, b1, w2, b2,
                                        w3, b3, off_w, dcn_w, offT, dcnT,
                                        feat2, featN);
    off_kernel<<<NWG, 256, 0, stream>>>(featN, offT, off_b, oo);
    dcn_kernel<<<NWG, 256, 0, stream>>>(feat2, oo, dcnT, dcn_b, out);
}

// Round 16
// 355.083 us; speedup vs baseline: 1.0056x; 1.0056x over previous
//
#include <hip/hip_runtime.h>
#include <math.h>

// Problem constants
#define CCH 64
#define HH  128
#define WW  128
#define NB  4
#define NPIX (NB*HH*WW)   // 65536
#define NWG  (NPIX/64)    // 1024 blocks for the pixel kernels

// XCD-aware block swizzle (T1): each XCD gets a contiguous 64-row slice.
__device__ __forceinline__ int swz_block(int bid) {
    return (bid & 7) * (NWG >> 3) + (bid >> 3);
}

// ---------------------------------------------------------------------------
// Kernel 1: prep (first 144 blocks) + fused 4-layer MLP -> feat2 (NHWC) and
// featN (NCHW aliased into d_out; dead until dcn's final write).
// ---------------------------------------------------------------------------
__global__ __launch_bounds__(256) void mlp_kernel(
    const float* __restrict__ ev, const float* __restrict__ im,
    const float* __restrict__ w0, const float* __restrict__ b0,
    const float* __restrict__ w1, const float* __restrict__ b1,
    const float* __restrict__ w2, const float* __restrict__ b2,
    const float* __restrict__ w3, const float* __restrict__ b3,
    const float* __restrict__ off_w, const float* __restrict__ dcn_w,
    float* __restrict__ offT, float* __restrict__ dcnT,
    float* __restrict__ feat2, float* __restrict__ featN)
{
    __shared__ float xA[64 * 65];   // [ch][px], padded
    __shared__ float xB[64 * 65];
    int tid  = threadIdx.x;

    // folded prep: transpose conv weights (blocks 0..143)
    if (blockIdx.x < 144) {
        int idx = blockIdx.x * 256 + tid;
        if (idx < 576 * 28) {
            int rc = idx / 28;       // ic*9+kk
            int o  = idx % 28;
            offT[rc * 28 + o] = (o < 27) ? off_w[o * 576 + rc] : 0.0f;
        }
        if (idx < 36864) {
            int o    = idx & 63;
            int rest = idx >> 6;
            int ic   = rest & 63;
            int k    = rest >> 6;
            dcnT[(k * 64 + ic) * 64 + o] = dcn_w[o * 576 + ic * 9 + k];
        }
    }

    int cg   = __builtin_amdgcn_readfirstlane(tid >> 6);
    int lane = tid & 63;
    int sw   = swz_block(blockIdx.x);
    int p = sw * 64 + lane;
    int b = p >> 14;
    int q = p & 16383;
    int h = q >> 7;
    int w = q & 127;
    int c0 = cg * 16;

    float acc[16];
#pragma unroll
    for (int j = 0; j < 16; ++j) acc[j] = b0[c0 + j];

    const float* evb = ev + ((b * 64) * 64 + (h >> 1)) * 64 + (w >> 1);
    for (int i = 0; i < 64; ++i) {
        float v = evb[i * 4096];
        const float* wr = w0 + i * 64 + c0;
#pragma unroll
        for (int j = 0; j < 16; ++j) acc[j] = fmaf(v, wr[j], acc[j]);
    }
    const float* imb = im + ((b * 64) * 128 + h) * 128 + w;
    for (int i = 0; i < 64; ++i) {
        float v = imb[i * 16384];
        const float* wr = w0 + (64 + i) * 64 + c0;
#pragma unroll
        for (int j = 0; j < 16; ++j) acc[j] = fmaf(v, wr[j], acc[j]);
    }
    {
        float rely = (h & 1) ? 0.5f : -0.5f;
        float relx = (w & 1) ? 0.5f : -0.5f;
        const float* wr = w0 + 128 * 64 + c0;
#pragma unroll
        for (int j = 0; j < 16; ++j) acc[j] = fmaf(rely, wr[j], acc[j]);
#pragma unroll
        for (int j = 0; j < 16; ++j) acc[j] = fmaf(relx, wr[64 + j], acc[j]);
#pragma unroll
        for (int j = 0; j < 16; ++j) acc[j] += wr[128 + j] + wr[192 + j];
    }
#pragma unroll
    for (int j = 0; j < 16; ++j) xA[(c0 + j) * 65 + lane] = fmaxf(acc[j], 0.0f);
    __syncthreads();

#pragma unroll
    for (int j = 0; j < 16; ++j) acc[j] = b1[c0 + j];
    for (int i = 0; i < 64; ++i) {
        float v = xA[i * 65 + lane];
        const float* wr = w1 + i * 64 + c0;
#pragma unroll
        for (int j = 0; j < 16; ++j) acc[j] = fmaf(v, wr[j], acc[j]);
    }
#pragma unroll
    for (int j = 0; j < 16; ++j) xB[(c0 + j) * 65 + lane] = fmaxf(acc[j], 0.0f);
    __syncthreads();

#pragma unroll
    for (int j = 0; j < 16; ++j) acc[j] = b2[c0 + j];
    for (int i = 0; i < 64; ++i) {
        float v = xB[i * 65 + lane];
        const float* wr = w2 + i * 64 + c0;
#pragma unroll
        for (int j = 0; j < 16; ++j) acc[j] = fmaf(v, wr[j], acc[j]);
    }
#pragma unroll
    for (int j = 0; j < 16; ++j) xA[(c0 + j) * 65 + lane] = fmaxf(acc[j], 0.0f);
    __syncthreads();

#pragma unroll
    for (int j = 0; j < 16; ++j) acc[j] = b3[c0 + j];
    for (int i = 0; i < 64; ++i) {
        float v = xA[i * 65 + lane];
        const float* wr = w3 + i * 64 + c0;
#pragma unroll
        for (int j = 0; j < 16; ++j) acc[j] = fmaf(v, wr[j], acc[j]);
    }

    // NCHW store (coalesced: lanes = consecutive px)
    float* fbN = featN + (b * 64 + c0) * 16384 + q;
#pragma unroll
    for (int j = 0; j < 16; ++j) fbN[j * 16384] = acc[j];

    // NHWC store via padded-LDS transpose (coalesced float4)
#pragma unroll
    for (int j = 0; j < 16; ++j) xB[(c0 + j) * 65 + lane] = acc[j];
    __syncthreads();
    {
        int q0 = (sw * 64) & 16383;
        float* fb = feat2 + ((size_t)b * 16384 + q0) * 64;
        int ch0 = (tid & 15) * 4;
#pragma unroll
        for (int r = 0; r < 4; ++r) {
            int px = (tid >> 4) + r * 16;
            float4 v = make_float4(xB[(ch0 + 0) * 65 + px],
                                   xB[(ch0 + 1) * 65 + px],
                                   xB[(ch0 + 2) * 65 + px],
                                   xB[(ch0 + 3) * 65 + px]);
            ((float4*)fb)[tid + r * 256] = v;
        }
    }
}

// ---------------------------------------------------------------------------
// Kernel 2: 3x3 offset conv -> raw 27-ch oo.  NCHW reads (featN in d_out).
// ---------------------------------------------------------------------------
__global__ __launch_bounds__(256) void off_kernel(
    const float* __restrict__ featN, const float* __restrict__ offT,
    const float* __restrict__ off_b,
    float* __restrict__ oo)
{
    __shared__ float po[4 * 27 * 64];   // [wave][o][px]
    int tid  = threadIdx.x;
    int wv   = __builtin_amdgcn_readfirstlane(tid >> 6);
    int lane = tid & 63;
    int p = swz_block(blockIdx.x) * 64 + lane;
    int b = p >> 14;
    int q = p & 16383;
    int h = q >> 7;
    int w = q & 127;
    int c0 = wv * 16;

    float acc[27];
#pragma unroll
    for (int o = 0; o < 27; ++o) acc[o] = 0.0f;

    const float* fb = featN + (b * 64 + c0) * 16384;
    for (int i = 0; i < 16; ++i) {
        const float* f = fb + i * 16384;
        float v[9];
#pragma unroll
        for (int ky = 0; ky < 3; ++ky)
#pragma unroll
            for (int kx = 0; kx < 3; ++kx) {
                int y = h + ky - 1, x = w + kx - 1;
                bool ok = (y >= 0) && (y < 128) && (x >= 0) && (x < 128);
                v[ky * 3 + kx] = ok ? f[y * 128 + x] : 0.0f;
            }
#pragma unroll
        for (int kk = 0; kk < 9; ++kk) {
            const float* wr = offT + ((c0 + i) * 9 + kk) * 28;
#pragma unroll
            for (int o = 0; o < 27; ++o) acc[o] = fmaf(v[kk], wr[o], acc[o]);
        }
    }

#pragma unroll
    for (int o = 0; o < 27; ++o) po[(wv * 27 + o) * 64 + lane] = acc[o];
    __syncthreads();

#pragma unroll
    for (int j = 0; j < 7; ++j) {
        int o = wv + 4 * j;
        if (o < 27) {
            float s = off_b[o]
                    + po[o * 64 + lane] + po[(27 + o) * 64 + lane]
                    + po[(54 + o) * 64 + lane] + po[(81 + o) * 64 + lane];
            oo[((b * 27 + o) << 14) + q] = s;
        }
    }
}

// ---------------------------------------------------------------------------
// Kernel 3: transform + deformable sampling + einsum + bias.
// r14 structure with LDS traffic halved:
//  - sample LDS paired as float2 [pair][px]: writes 8 x b64, reads b64
//  - own 16-ic slice forwarded in registers across the barrier (own[16]),
//    only the 48 foreign ic read from LDS (24 x ds_read_b64 per k)
// FMA body keeps the proven scalar-sample x SGPR-weight-row pattern.
// ---------------------------------------------------------------------------
__device__ __forceinline__ void dcn_transform_r(
    float oy, float ox, float mlraw, int k, int h, int w,
    float& W00, float& W01, float& W10, float& W11,
    int& i00, int& i01, int& i10, int& i11)
{
    float ml = 1.0f / (1.0f + expf(-mlraw));
    float py = (float)(h + k / 3 - 1) + oy;
    float px = (float)(w + k % 3 - 1) + ox;

    float y0f = floorf(py), x0f = floorf(px);
    float ly = py - y0f, lx = px - x0f;
    int y0 = (int)y0f, x0 = (int)x0f;

    bool vy0 = (y0f >= 0.0f)        && (y0f <= 127.0f);
    bool vy1 = (y0f + 1.0f >= 0.0f) && (y0f + 1.0f <= 127.0f);
    bool vx0 = (x0f >= 0.0f)        && (x0f <= 127.0f);
    bool vx1 = (x0f + 1.0f >= 0.0f) && (x0f + 1.0f <= 127.0f);

    int yc0 = min(max(y0, 0), 127),     yc1 = min(max(y0 + 1, 0), 127);
    int xc0 = min(max(x0, 0), 127),     xc1 = min(max(x0 + 1, 0), 127);

    W00 = (1.0f - ly) * (1.0f - lx) * ml * ((vy0 && vx0) ? 1.0f : 0.0f);
    W01 = (1.0f - ly) * lx          * ml * ((vy0 && vx1) ? 1.0f : 0.0f);
    W10 = ly * (1.0f - lx)          * ml * ((vy1 && vx0) ? 1.0f : 0.0f);
    W11 = ly * lx                   * ml * ((vy1 && vx1) ? 1.0f : 0.0f);

    i00 = yc0 * 128 + xc0; i01 = yc0 * 128 + xc1;
    i10 = yc1 * 128 + xc0; i11 = yc1 * 128 + xc1;
}

__global__ __launch_bounds__(256) void dcn_kernel(
    const float* __restrict__ feat2,
    const float* __restrict__ oo,
    const float* __restrict__ dcnT, const float* __restrict__ dcn_b,
    float* __restrict__ out)
{
    __shared__ float2 sA2[32 * 64];   // [pair][px], 16 KB
    __shared__ float2 sB2[32 * 64];
    int tid  = threadIdx.x;
    int wv   = __builtin_amdgcn_readfirstlane(tid >> 6);
    int lane = tid & 63;
    int p = swz_block(blockIdx.x) * 64 + lane;
    int b = p >> 14;
    int q = p & 16383;
    int h = q >> 7;
    int w = q & 127;
    int c0 = wv * 16;        // this wave's ic slice AND o slice
    int pb0 = wv * 8;        // this wave's pair base

    float acc[16];
#pragma unroll
    for (int j = 0; j < 16; ++j) acc[j] = dcn_b[c0 + j];

    float own[16];           // this wave's blended samples (own lane's px)

    const float* fb2 = feat2 + (b * 16384) * 64 + c0;   // wave's 16-ic slice
    const float* oob = oo + ((b * 27) << 14) + q;

    // ---- prologue: k=0 transform+gather into sA2 + own[]; prefetch k=1 oo --
    {
        float oy = oob[0];
        float ox = oob[1 << 14];
        float om = oob[18 << 14];
        float W00, W01, W10, W11; int i00, i01, i10, i11;
        dcn_transform_r(oy, ox, om, 0, h, w, W00, W01, W10, W11, i00, i01, i10, i11);
        const float4* p00 = (const float4*)(fb2 + i00 * 64);
        const float4* p01 = (const float4*)(fb2 + i01 * 64);
        const float4* p10 = (const float4*)(fb2 + i10 * 64);
        const float4* p11 = (const float4*)(fb2 + i11 * 64);
#pragma unroll
        for (int g = 0; g < 4; ++g) {
            float4 a = p00[g], bb = p01[g], c = p10[g], d = p11[g];
            own[4 * g + 0] = W00 * a.x + W01 * bb.x + W10 * c.x + W11 * d.x;
            own[4 * g + 1] = W00 * a.y + W01 * bb.y + W10 * c.y + W11 * d.y;
            own[4 * g + 2] = W00 * a.z + W01 * bb.z + W10 * c.z + W11 * d.z;
            own[4 * g + 3] = W00 * a.w + W01 * bb.w + W10 * c.w + W11 * d.w;
            sA2[(pb0 + 2 * g) * 64 + lane]     = make_float2(own[4 * g + 0], own[4 * g + 1]);
            sA2[(pb0 + 2 * g + 1) * 64 + lane] = make_float2(own[4 * g + 2], own[4 * g + 3]);
        }
    }
    float oyN = oob[2 << 14];
    float oxN = oob[3 << 14];
    float omN = oob[19 << 14];
    __syncthreads();

    float2* cur = sA2;
    float2* nxt = sB2;

    for (int k = 0; k < 9; ++k) {
        bool pre = (k < 8);
        float W00, W01, W10, W11; int i00, i01, i10, i11;
        float4 a0, a1, b0, b1, c0v, c1v, d0, d1;
        const float4 *p00 = nullptr, *p01 = nullptr, *p10 = nullptr, *p11 = nullptr;

        if (pre) {
            dcn_transform_r(oyN, oxN, omN, k + 1, h, w,
                            W00, W01, W10, W11, i00, i01, i10, i11);
            if (k < 7) {
                oyN = oob[(2 * (k + 2)) << 14];
                oxN = oob[(2 * (k + 2) + 1) << 14];
                omN = oob[(18 + (k + 2)) << 14];
            }
            p00 = (const float4*)(fb2 + i00 * 64);
            p01 = (const float4*)(fb2 + i01 * 64);
            p10 = (const float4*)(fb2 + i10 * 64);
            p11 = (const float4*)(fb2 + i11 * 64);
            a0 = p00[0]; a1 = p00[1];
            b0 = p01[0]; b1 = p01[1];
            c0v = p10[0]; c1v = p10[1];
            d0 = p11[0]; d1 = p11[1];
        }

        const float* wk = dcnT + (k * 64) * 64 + c0;

        // FMA phase A: own 16 ic from registers (no LDS)
#pragma unroll
        for (int i = 0; i < 16; ++i) {
            float s = own[i];
            const float* wr = wk + (c0 + i) * 64;
#pragma unroll
            for (int j = 0; j < 16; ++j) acc[j] = fmaf(s, wr[j], acc[j]);
        }

        if (pre) {
            // blend batch 0 -> own[0..7] (for k+1) + LDS pairs
            own[0] = W00 * a0.x + W01 * b0.x + W10 * c0v.x + W11 * d0.x;
            own[1] = W00 * a0.y + W01 * b0.y + W10 * c0v.y + W11 * d0.y;
            own[2] = W00 * a0.z + W01 * b0.z + W10 * c0v.z + W11 * d0.z;
            own[3] = W00 * a0.w + W01 * b0.w + W10 * c0v.w + W11 * d0.w;
            own[4] = W00 * a1.x + W01 * b1.x + W10 * c1v.x + W11 * d1.x;
            own[5] = W00 * a1.y + W01 * b1.y + W10 * c1v.y + W11 * d1.y;
            own[6] = W00 * a1.z + W01 * b1.z + W10 * c1v.z + W11 * d1.z;
            own[7] = W00 * a1.w + W01 * b1.w + W10 * c1v.w + W11 * d1.w;
            nxt[(pb0 + 0) * 64 + lane] = make_float2(own[0], own[1]);
            nxt[(pb0 + 1) * 64 + lane] = make_float2(own[2], own[3]);
            nxt[(pb0 + 2) * 64 + lane] = make_float2(own[4], own[5]);
            nxt[(pb0 + 3) * 64 + lane] = make_float2(own[6], own[7]);
            a0 = p00[2]; a1 = p00[3];
            b0 = p01[2]; b1 = p01[3];
            c0v = p10[2]; c1v = p10[3];
            d0 = p11[2]; d1 = p11[3];
        }

        // FMA phase B: foreign slices +1, +2 (16 pairs via ds_read_b64)
#pragma unroll
        for (int ws = 1; ws <= 2; ++ws) {
            int fw = (wv + ws) & 3;
            int pb = fw * 8;
            const float* wf = wk + (fw * 16) * 64;
#pragma unroll
            for (int g = 0; g < 8; ++g) {
                float2 sv = cur[(pb + g) * 64 + lane];
                const float* wr = wf + (2 * g) * 64;
#pragma unroll
                for (int j = 0; j < 16; ++j) acc[j] = fmaf(sv.x, wr[j], acc[j]);
#pragma unroll
                for (int j = 0; j < 16; ++j) acc[j] = fmaf(sv.y, wr[64 + j], acc[j]);
            }
        }

        if (pre) {
            // blend batch 1 -> own[8..15] + LDS pairs
            own[8]  = W00 * a0.x + W01 * b0.x + W10 * c0v.x + W11 * d0.x;
            own[9]  = W00 * a0.y + W01 * b0.y + W10 * c0v.y + W11 * d0.y;
            own[10] = W00 * a0.z + W01 * b0.z + W10 * c0v.z + W11 * d0.z;
            own[11] = W00 * a0.w + W01 * b0.w + W10 * c0v.w + W11 * d0.w;
            own[12] = W00 * a1.x + W01 * b1.x + W10 * c1v.x + W11 * d1.x;
            own[13] = W00 * a1.y + W01 * b1.y + W10 * c1v.y + W11 * d1.y;
            own[14] = W00 * a1.z + W01 * b1.z + W10 * c1v.z + W11 * d1.z;
            own[15] = W00 * a1.w + W01 * b1.w + W10 * c1v.w + W11 * d1.w;
            nxt[(pb0 + 4) * 64 + lane] = make_float2(own[8],  own[9]);
            nxt[(pb0 + 5) * 64 + lane] = make_float2(own[10], own[11]);
            nxt[(pb0 + 6) * 64 + lane] = make_float2(own[12], own[13]);
            nxt[(pb0 + 7) * 64 + lane] = make_float2(own[14], own[15]);
        }

        // FMA phase C: foreign slice +3 (8 pairs)
        {
            int fw = (wv + 3) & 3;
            int pb = fw * 8;
            const float* wf = wk + (fw * 16) * 64;
#pragma unroll
            for (int g = 0; g < 8; ++g) {
                float2 sv = cur[(pb + g) * 64 + lane];
                const float* wr = wf + (2 * g) * 64;
#pragma unroll
                for (int j = 0; j < 16; ++j) acc[j] = fmaf(sv.x, wr[j], acc[j]);
#pragma unroll
                for (int j = 0; j < 16; ++j) acc[j] = fmaf(sv.y, wr[64 + j], acc[j]);
            }
        }

        __syncthreads();
        float2* t = cur; cur = nxt; nxt = t;
    }

    float* ob = out + (b * 64 + c0) * 16384 + q;
#pragma unroll
    for (int j = 0; j < 16; ++j) ob[j * 16384] = acc[j];
}

// ---------------------------------------------------------------------------
extern "C" void kernel_launch(void* const* d_in, const int* in_sizes, int n_in,
                              void* d_out, int out_size, void* d_ws, size_t ws_size,
                              hipStream_t stream)
{
    const float* ev    = (const float*)d_in[0];
    const float* im    = (const float*)d_in[1];
    const float* w0    = (const float*)d_in[2];
    const float* b0    = (const float*)d_in[3];
    const float* w1    = (const float*)d_in[4];
    const float* b1    = (const float*)d_in[5];
    const float* w2    = (const float*)d_in[6];
    const float* b2    = (const float*)d_in[7];
    const float* w3    = (const float*)d_in[8];
    const float* b3    = (const float*)d_in[9];
    const float* off_w = (const float*)d_in[10];
    const float* off_b = (const float*)d_in[11];
    const float* dcn_w = (const float*)d_in[12];
    const float* dcn_b = (const float*)d_in[13];
    float* out = (float*)d_out;

    char* ws = (char*)d_ws;
    float* feat2 = (float*)(ws);                       // 16,777,216 B (NHWC)
    float* oo    = (float*)(ws + 16777216);            //  7,077,888 B
    float* offT  = (float*)(ws + 23855104);            //     64,512 B
    float* dcnT  = (float*)(ws + 23920640);            //    147,456 B
    float* featN = out;   // NCHW copy aliased into d_out (dead before dcn's write)

    mlp_kernel<<<NWG, 256, 0, stream>>>(ev, im, w0, b0, w1, b1, w2, b2,
                                        w3, b3, off_w, dcn_w, offT, dcnT,
                                        feat2, featN);
    off_kernel<<<NWG, 256, 0, stream>>>(featN, offT, off_b, oo);
    dcn_kernel<<<NWG, 256, 0, stream>>>(feat2, oo, dcnT, dcn_b, out);
}

// Round 17
// 317.217 us; speedup vs baseline: 1.1256x; 1.1194x over previous
//
#include <hip/hip_runtime.h>
#include <math.h>

// Problem constants
#define CCH 64
#define HH  128
#define WW  128
#define NB  4
#define NPIX (NB*HH*WW)   // 65536
#define NWG  (NPIX/64)    // 1024 blocks for the pixel kernels

// XCD-aware block swizzle (T1): each XCD gets a contiguous 64-row slice.
__device__ __forceinline__ int swz_block(int bid) {
    return (bid & 7) * (NWG >> 3) + (bid >> 3);
}

// ---------------------------------------------------------------------------
// Kernel 1: prep (first 144 blocks) + fused 4-layer MLP -> feat2 (NHWC) and
// featN (NCHW aliased into d_out; dead until dcn's final write).
// ---------------------------------------------------------------------------
__global__ __launch_bounds__(256) void mlp_kernel(
    const float* __restrict__ ev, const float* __restrict__ im,
    const float* __restrict__ w0, const float* __restrict__ b0,
    const float* __restrict__ w1, const float* __restrict__ b1,
    const float* __restrict__ w2, const float* __restrict__ b2,
    const float* __restrict__ w3, const float* __restrict__ b3,
    const float* __restrict__ off_w, const float* __restrict__ dcn_w,
    float* __restrict__ offT, float* __restrict__ dcnT,
    float* __restrict__ feat2, float* __restrict__ featN)
{
    __shared__ float xA[64 * 65];   // [ch][px], padded
    __shared__ float xB[64 * 65];
    int tid  = threadIdx.x;

    // folded prep: transpose conv weights (blocks 0..143)
    if (blockIdx.x < 144) {
        int idx = blockIdx.x * 256 + tid;
        if (idx < 576 * 28) {
            int rc = idx / 28;       // ic*9+kk
            int o  = idx % 28;
            offT[rc * 28 + o] = (o < 27) ? off_w[o * 576 + rc] : 0.0f;
        }
        if (idx < 36864) {
            int o    = idx & 63;
            int rest = idx >> 6;
            int ic   = rest & 63;
            int k    = rest >> 6;
            dcnT[(k * 64 + ic) * 64 + o] = dcn_w[o * 576 + ic * 9 + k];
        }
    }

    int cg   = __builtin_amdgcn_readfirstlane(tid >> 6);
    int lane = tid & 63;
    int sw   = swz_block(blockIdx.x);
    int p = sw * 64 + lane;
    int b = p >> 14;
    int q = p & 16383;
    int h = q >> 7;
    int w = q & 127;
    int c0 = cg * 16;

    float acc[16];
#pragma unroll
    for (int j = 0; j < 16; ++j) acc[j] = b0[c0 + j];

    const float* evb = ev + ((b * 64) * 64 + (h >> 1)) * 64 + (w >> 1);
    for (int i = 0; i < 64; ++i) {
        float v = evb[i * 4096];
        const float* wr = w0 + i * 64 + c0;
#pragma unroll
        for (int j = 0; j < 16; ++j) acc[j] = fmaf(v, wr[j], acc[j]);
    }
    const float* imb = im + ((b * 64) * 128 + h) * 128 + w;
    for (int i = 0; i < 64; ++i) {
        float v = imb[i * 16384];
        const float* wr = w0 + (64 + i) * 64 + c0;
#pragma unroll
        for (int j = 0; j < 16; ++j) acc[j] = fmaf(v, wr[j], acc[j]);
    }
    {
        float rely = (h & 1) ? 0.5f : -0.5f;
        float relx = (w & 1) ? 0.5f : -0.5f;
        const float* wr = w0 + 128 * 64 + c0;
#pragma unroll
        for (int j = 0; j < 16; ++j) acc[j] = fmaf(rely, wr[j], acc[j]);
#pragma unroll
        for (int j = 0; j < 16; ++j) acc[j] = fmaf(relx, wr[64 + j], acc[j]);
#pragma unroll
        for (int j = 0; j < 16; ++j) acc[j] += wr[128 + j] + wr[192 + j];
    }
#pragma unroll
    for (int j = 0; j < 16; ++j) xA[(c0 + j) * 65 + lane] = fmaxf(acc[j], 0.0f);
    __syncthreads();

#pragma unroll
    for (int j = 0; j < 16; ++j) acc[j] = b1[c0 + j];
    for (int i = 0; i < 64; ++i) {
        float v = xA[i * 65 + lane];
        const float* wr = w1 + i * 64 + c0;
#pragma unroll
        for (int j = 0; j < 16; ++j) acc[j] = fmaf(v, wr[j], acc[j]);
    }
#pragma unroll
    for (int j = 0; j < 16; ++j) xB[(c0 + j) * 65 + lane] = fmaxf(acc[j], 0.0f);
    __syncthreads();

#pragma unroll
    for (int j = 0; j < 16; ++j) acc[j] = b2[c0 + j];
    for (int i = 0; i < 64; ++i) {
        float v = xB[i * 65 + lane];
        const float* wr = w2 + i * 64 + c0;
#pragma unroll
        for (int j = 0; j < 16; ++j) acc[j] = fmaf(v, wr[j], acc[j]);
    }
#pragma unroll
    for (int j = 0; j < 16; ++j) xA[(c0 + j) * 65 + lane] = fmaxf(acc[j], 0.0f);
    __syncthreads();

#pragma unroll
    for (int j = 0; j < 16; ++j) acc[j] = b3[c0 + j];
    for (int i = 0; i < 64; ++i) {
        float v = xA[i * 65 + lane];
        const float* wr = w3 + i * 64 + c0;
#pragma unroll
        for (int j = 0; j < 16; ++j) acc[j] = fmaf(v, wr[j], acc[j]);
    }

    // NCHW store (coalesced: lanes = consecutive px)
    float* fbN = featN + (b * 64 + c0) * 16384 + q;
#pragma unroll
    for (int j = 0; j < 16; ++j) fbN[j * 16384] = acc[j];

    // NHWC store via padded-LDS transpose (coalesced float4)
#pragma unroll
    for (int j = 0; j < 16; ++j) xB[(c0 + j) * 65 + lane] = acc[j];
    __syncthreads();
    {
        int q0 = (sw * 64) & 16383;
        float* fb = feat2 + ((size_t)b * 16384 + q0) * 64;
        int ch0 = (tid & 15) * 4;
#pragma unroll
        for (int r = 0; r < 4; ++r) {
            int px = (tid >> 4) + r * 16;
            float4 v = make_float4(xB[(ch0 + 0) * 65 + px],
                                   xB[(ch0 + 1) * 65 + px],
                                   xB[(ch0 + 2) * 65 + px],
                                   xB[(ch0 + 3) * 65 + px]);
            ((float4*)fb)[tid + r * 256] = v;
        }
    }
}

// ---------------------------------------------------------------------------
// Kernel 2: 3x3 offset conv -> raw 27-ch oo.  NCHW reads (featN in d_out).
// ---------------------------------------------------------------------------
__global__ __launch_bounds__(256) void off_kernel(
    const float* __restrict__ featN, const float* __restrict__ offT,
    const float* __restrict__ off_b,
    float* __restrict__ oo)
{
    __shared__ float po[4 * 27 * 64];   // [wave][o][px]
    int tid  = threadIdx.x;
    int wv   = __builtin_amdgcn_readfirstlane(tid >> 6);
    int lane = tid & 63;
    int p = swz_block(blockIdx.x) * 64 + lane;
    int b = p >> 14;
    int q = p & 16383;
    int h = q >> 7;
    int w = q & 127;
    int c0 = wv * 16;

    float acc[27];
#pragma unroll
    for (int o = 0; o < 27; ++o) acc[o] = 0.0f;

    const float* fb = featN + (b * 64 + c0) * 16384;
    for (int i = 0; i < 16; ++i) {
        const float* f = fb + i * 16384;
        float v[9];
#pragma unroll
        for (int ky = 0; ky < 3; ++ky)
#pragma unroll
            for (int kx = 0; kx < 3; ++kx) {
                int y = h + ky - 1, x = w + kx - 1;
                bool ok = (y >= 0) && (y < 128) && (x >= 0) && (x < 128);
                v[ky * 3 + kx] = ok ? f[y * 128 + x] : 0.0f;
            }
#pragma unroll
        for (int kk = 0; kk < 9; ++kk) {
            const float* wr = offT + ((c0 + i) * 9 + kk) * 28;
#pragma unroll
            for (int o = 0; o < 27; ++o) acc[o] = fmaf(v[kk], wr[o], acc[o]);
        }
    }

#pragma unroll
    for (int o = 0; o < 27; ++o) po[(wv * 27 + o) * 64 + lane] = acc[o];
    __syncthreads();

#pragma unroll
    for (int j = 0; j < 7; ++j) {
        int o = wv + 4 * j;
        if (o < 27) {
            float s = off_b[o]
                    + po[o * 64 + lane] + po[(27 + o) * 64 + lane]
                    + po[(54 + o) * 64 + lane] + po[(81 + o) * 64 + lane];
            oo[((b * 27 + o) << 14) + q] = s;
        }
    }
}

// ---------------------------------------------------------------------------
// Kernel 3: transform + deformable sampling + einsum + bias.
// SHARE-NOTHING: every wave gathers ALL 64 ic for its own lanes' pixels
// (the 4 waves of a block issue IDENTICAL address streams -> L1 hits for
// followers; one barrier per k keeps them converged). Zero LDS, zero bank
// conflicts, samples feed FMAs straight from registers, weights stay
// wave-uniform s_loads. oo prefetched in registers (r14-proven).
// ---------------------------------------------------------------------------
__device__ __forceinline__ void dcn_transform_r(
    float oy, float ox, float mlraw, int k, int h, int w,
    float& W00, float& W01, float& W10, float& W11,
    int& i00, int& i01, int& i10, int& i11)
{
    float ml = 1.0f / (1.0f + expf(-mlraw));
    float py = (float)(h + k / 3 - 1) + oy;
    float px = (float)(w + k % 3 - 1) + ox;

    float y0f = floorf(py), x0f = floorf(px);
    float ly = py - y0f, lx = px - x0f;
    int y0 = (int)y0f, x0 = (int)x0f;

    bool vy0 = (y0f >= 0.0f)        && (y0f <= 127.0f);
    bool vy1 = (y0f + 1.0f >= 0.0f) && (y0f + 1.0f <= 127.0f);
    bool vx0 = (x0f >= 0.0f)        && (x0f <= 127.0f);
    bool vx1 = (x0f + 1.0f >= 0.0f) && (x0f + 1.0f <= 127.0f);

    int yc0 = min(max(y0, 0), 127),     yc1 = min(max(y0 + 1, 0), 127);
    int xc0 = min(max(x0, 0), 127),     xc1 = min(max(x0 + 1, 0), 127);

    W00 = (1.0f - ly) * (1.0f - lx) * ml * ((vy0 && vx0) ? 1.0f : 0.0f);
    W01 = (1.0f - ly) * lx          * ml * ((vy0 && vx1) ? 1.0f : 0.0f);
    W10 = ly * (1.0f - lx)          * ml * ((vy1 && vx0) ? 1.0f : 0.0f);
    W11 = ly * lx                   * ml * ((vy1 && vx1) ? 1.0f : 0.0f);

    i00 = yc0 * 128 + xc0; i01 = yc0 * 128 + xc1;
    i10 = yc1 * 128 + xc0; i11 = yc1 * 128 + xc1;
}

__global__ __launch_bounds__(256) void dcn_kernel(
    const float* __restrict__ feat2,
    const float* __restrict__ oo,
    const float* __restrict__ dcnT, const float* __restrict__ dcn_b,
    float* __restrict__ out)
{
    int tid  = threadIdx.x;
    int wv   = __builtin_amdgcn_readfirstlane(tid >> 6);
    int lane = tid & 63;
    int p = swz_block(blockIdx.x) * 64 + lane;
    int b = p >> 14;
    int q = p & 16383;
    int h = q >> 7;
    int w = q & 127;
    int c0 = wv * 16;        // this wave's OUTPUT slice

    float acc[16];
#pragma unroll
    for (int j = 0; j < 16; ++j) acc[j] = dcn_b[c0 + j];

    const float* fb2 = feat2 + (size_t)(b * 16384) * 64;   // full NHWC base
    const float* oob = oo + ((b * 27) << 14) + q;

    // prefetch oo for k=0
    float oyN = oob[0];
    float oxN = oob[1 << 14];
    float omN = oob[18 << 14];

    for (int k = 0; k < 9; ++k) {
        float W00, W01, W10, W11; int i00, i01, i10, i11;
        dcn_transform_r(oyN, oxN, omN, k, h, w, W00, W01, W10, W11,
                        i00, i01, i10, i11);
        if (k < 8) {   // prefetch next k's oo (hides under this k's work)
            oyN = oob[(2 * (k + 1)) << 14];
            oxN = oob[(2 * (k + 1) + 1) << 14];
            omN = oob[(18 + (k + 1)) << 14];
        }

        const float* pc00 = fb2 + i00 * 64;
        const float* pc01 = fb2 + i01 * 64;
        const float* pc10 = fb2 + i10 * 64;
        const float* pc11 = fb2 + i11 * 64;
        const float* wk   = dcnT + (size_t)k * 4096 + c0;

        // keep the block's 4 waves converged so followers hit L1 on the
        // identical address stream
        __syncthreads();

        // stream all 64 ic in chunks of 4: load 4 corners' float4 -> blend
        // -> 64 FMAs against wave-uniform weight rows (s_load).
#pragma unroll 4
        for (int c = 0; c < 16; ++c) {
            float4 a  = *(const float4*)(pc00 + c * 4);
            float4 bb = *(const float4*)(pc01 + c * 4);
            float4 cc = *(const float4*)(pc10 + c * 4);
            float4 dd = *(const float4*)(pc11 + c * 4);
            float s0 = W00 * a.x + W01 * bb.x + W10 * cc.x + W11 * dd.x;
            float s1 = W00 * a.y + W01 * bb.y + W10 * cc.y + W11 * dd.y;
            float s2 = W00 * a.z + W01 * bb.z + W10 * cc.z + W11 * dd.z;
            float s3 = W00 * a.w + W01 * bb.w + W10 * cc.w + W11 * dd.w;
            const float* wr = wk + (4 * c) * 64;
#pragma unroll
            for (int j = 0; j < 16; ++j) acc[j] = fmaf(s0, wr[j], acc[j]);
#pragma unroll
            for (int j = 0; j < 16; ++j) acc[j] = fmaf(s1, wr[64 + j], acc[j]);
#pragma unroll
            for (int j = 0; j < 16; ++j) acc[j] = fmaf(s2, wr[128 + j], acc[j]);
#pragma unroll
            for (int j = 0; j < 16; ++j) acc[j] = fmaf(s3, wr[192 + j], acc[j]);
        }
    }

    float* ob = out + (b * 64 + c0) * 16384 + q;
#pragma unroll
    for (int j = 0; j < 16; ++j) ob[j * 16384] = acc[j];
}

// ---------------------------------------------------------------------------
extern "C" void kernel_launch(void* const* d_in, const int* in_sizes, int n_in,
                              void* d_out, int out_size, void* d_ws, size_t ws_size,
                              hipStream_t stream)
{
    const float* ev    = (const float*)d_in[0];
    const float* im    = (const float*)d_in[1];
    const float* w0    = (const float*)d_in[2];
    const float* b0    = (const float*)d_in[3];
    const float* w1    = (const float*)d_in[4];
    const float* b1    = (const float*)d_in[5];
    const float* w2    = (const float*)d_in[6];
    const float* b2    = (const float*)d_in[7];
    const float* w3    = (const float*)d_in[8];
    const float* b3    = (const float*)d_in[9];
    const float* off_w = (const float*)d_in[10];
    const float* off_b = (const float*)d_in[11];
    const float* dcn_w = (const float*)d_in[12];
    const float* dcn_b = (const float*)d_in[13];
    float* out = (float*)d_out;

    char* ws = (char*)d_ws;
    float* feat2 = (float*)(ws);                       // 16,777,216 B (NHWC)
    float* oo    = (float*)(ws + 16777216);            //  7,077,888 B
    float* offT  = (float*)(ws + 23855104);            //     64,512 B
    float* dcnT  = (float*)(ws + 23920640);            //    147,456 B
    float* featN = out;   // NCHW copy aliased into d_out (dead before dcn's write)

    mlp_kernel<<<NWG, 256, 0, stream>>>(ev, im, w0, b0, w1, b1, w2, b2,
                                        w3, b3, off_w, dcn_w, offT, dcnT,
                                        feat2, featN);
    off_kernel<<<NWG, 256, 0, stream>>>(featN, offT, off_b, oo);
    dcn_kernel<<<NWG, 256, 0, stream>>>(feat2, oo, dcnT, dcn_b, out);
}

// Round 18
// 187.877 us; speedup vs baseline: 1.9005x; 1.6884x over previous
//
#include <hip/hip_runtime.h>
#include <math.h>

// Problem constants
#define CCH 64
#define HH  128
#define WW  128
#define NB  4
#define NPIX (NB*HH*WW)   // 65536
#define NWG  (NPIX/64)    // 1024 pixel-tiles (64 px each)

// XCD-aware block swizzle (T1): each XCD gets a contiguous 64-row slice.
__device__ __forceinline__ int swz_block(int bid) {
    return (bid & 7) * (NWG >> 3) + (bid >> 3);
}

// ---------------------------------------------------------------------------
// Kernel 1: prep (first 144 blocks) + fused 4-layer MLP -> feat2 (NHWC) and
// featN (NCHW aliased into d_out; dead until init_out overwrites it).
// ---------------------------------------------------------------------------
__global__ __launch_bounds__(256) void mlp_kernel(
    const float* __restrict__ ev, const float* __restrict__ im,
    const float* __restrict__ w0, const float* __restrict__ b0,
    const float* __restrict__ w1, const float* __restrict__ b1,
    const float* __restrict__ w2, const float* __restrict__ b2,
    const float* __restrict__ w3, const float* __restrict__ b3,
    const float* __restrict__ off_w, const float* __restrict__ dcn_w,
    float* __restrict__ offT, float* __restrict__ dcnT,
    float* __restrict__ feat2, float* __restrict__ featN)
{
    __shared__ float xA[64 * 65];   // [ch][px], padded
    __shared__ float xB[64 * 65];
    int tid  = threadIdx.x;

    // folded prep: transpose conv weights (blocks 0..143)
    if (blockIdx.x < 144) {
        int idx = blockIdx.x * 256 + tid;
        if (idx < 576 * 28) {
            int rc = idx / 28;       // ic*9+kk
            int o  = idx % 28;
            offT[rc * 28 + o] = (o < 27) ? off_w[o * 576 + rc] : 0.0f;
        }
        if (idx < 36864) {
            int o    = idx & 63;
            int rest = idx >> 6;
            int ic   = rest & 63;
            int k    = rest >> 6;
            dcnT[(k * 64 + ic) * 64 + o] = dcn_w[o * 576 + ic * 9 + k];
        }
    }

    int cg   = __builtin_amdgcn_readfirstlane(tid >> 6);
    int lane = tid & 63;
    int sw   = swz_block(blockIdx.x);
    int p = sw * 64 + lane;
    int b = p >> 14;
    int q = p & 16383;
    int h = q >> 7;
    int w = q & 127;
    int c0 = cg * 16;

    float acc[16];
#pragma unroll
    for (int j = 0; j < 16; ++j) acc[j] = b0[c0 + j];

    const float* evb = ev + ((b * 64) * 64 + (h >> 1)) * 64 + (w >> 1);
    for (int i = 0; i < 64; ++i) {
        float v = evb[i * 4096];
        const float* wr = w0 + i * 64 + c0;
#pragma unroll
        for (int j = 0; j < 16; ++j) acc[j] = fmaf(v, wr[j], acc[j]);
    }
    const float* imb = im + ((b * 64) * 128 + h) * 128 + w;
    for (int i = 0; i < 64; ++i) {
        float v = imb[i * 16384];
        const float* wr = w0 + (64 + i) * 64 + c0;
#pragma unroll
        for (int j = 0; j < 16; ++j) acc[j] = fmaf(v, wr[j], acc[j]);
    }
    {
        float rely = (h & 1) ? 0.5f : -0.5f;
        float relx = (w & 1) ? 0.5f : -0.5f;
        const float* wr = w0 + 128 * 64 + c0;
#pragma unroll
        for (int j = 0; j < 16; ++j) acc[j] = fmaf(rely, wr[j], acc[j]);
#pragma unroll
        for (int j = 0; j < 16; ++j) acc[j] = fmaf(relx, wr[64 + j], acc[j]);
#pragma unroll
        for (int j = 0; j < 16; ++j) acc[j] += wr[128 + j] + wr[192 + j];
    }
#pragma unroll
    for (int j = 0; j < 16; ++j) xA[(c0 + j) * 65 + lane] = fmaxf(acc[j], 0.0f);
    __syncthreads();

#pragma unroll
    for (int j = 0; j < 16; ++j) acc[j] = b1[c0 + j];
    for (int i = 0; i < 64; ++i) {
        float v = xA[i * 65 + lane];
        const float* wr = w1 + i * 64 + c0;
#pragma unroll
        for (int j = 0; j < 16; ++j) acc[j] = fmaf(v, wr[j], acc[j]);
    }
#pragma unroll
    for (int j = 0; j < 16; ++j) xB[(c0 + j) * 65 + lane] = fmaxf(acc[j], 0.0f);
    __syncthreads();

#pragma unroll
    for (int j = 0; j < 16; ++j) acc[j] = b2[c0 + j];
    for (int i = 0; i < 64; ++i) {
        float v = xB[i * 65 + lane];
        const float* wr = w2 + i * 64 + c0;
#pragma unroll
        for (int j = 0; j < 16; ++j) acc[j] = fmaf(v, wr[j], acc[j]);
    }
#pragma unroll
    for (int j = 0; j < 16; ++j) xA[(c0 + j) * 65 + lane] = fmaxf(acc[j], 0.0f);
    __syncthreads();

#pragma unroll
    for (int j = 0; j < 16; ++j) acc[j] = b3[c0 + j];
    for (int i = 0; i < 64; ++i) {
        float v = xA[i * 65 + lane];
        const float* wr = w3 + i * 64 + c0;
#pragma unroll
        for (int j = 0; j < 16; ++j) acc[j] = fmaf(v, wr[j], acc[j]);
    }

    // NCHW store (coalesced: lanes = consecutive px)
    float* fbN = featN + (b * 64 + c0) * 16384 + q;
#pragma unroll
    for (int j = 0; j < 16; ++j) fbN[j * 16384] = acc[j];

    // NHWC store via padded-LDS transpose (coalesced float4)
#pragma unroll
    for (int j = 0; j < 16; ++j) xB[(c0 + j) * 65 + lane] = acc[j];
    __syncthreads();
    {
        int q0 = (sw * 64) & 16383;
        float* fb = feat2 + ((size_t)b * 16384 + q0) * 64;
        int ch0 = (tid & 15) * 4;
#pragma unroll
        for (int r = 0; r < 4; ++r) {
            int px = (tid >> 4) + r * 16;
            float4 v = make_float4(xB[(ch0 + 0) * 65 + px],
                                   xB[(ch0 + 1) * 65 + px],
                                   xB[(ch0 + 2) * 65 + px],
                                   xB[(ch0 + 3) * 65 + px]);
            ((float4*)fb)[tid + r * 256] = v;
        }
    }
}

// ---------------------------------------------------------------------------
// Kernel 2: 3x3 offset conv -> raw 27-ch oo.  NCHW reads (featN in d_out).
// ---------------------------------------------------------------------------
__global__ __launch_bounds__(256) void off_kernel(
    const float* __restrict__ featN, const float* __restrict__ offT,
    const float* __restrict__ off_b,
    float* __restrict__ oo)
{
    __shared__ float po[4 * 27 * 64];   // [wave][o][px]
    int tid  = threadIdx.x;
    int wv   = __builtin_amdgcn_readfirstlane(tid >> 6);
    int lane = tid & 63;
    int p = swz_block(blockIdx.x) * 64 + lane;
    int b = p >> 14;
    int q = p & 16383;
    int h = q >> 7;
    int w = q & 127;
    int c0 = wv * 16;

    float acc[27];
#pragma unroll
    for (int o = 0; o < 27; ++o) acc[o] = 0.0f;

    const float* fb = featN + (b * 64 + c0) * 16384;
    for (int i = 0; i < 16; ++i) {
        const float* f = fb + i * 16384;
        float v[9];
#pragma unroll
        for (int ky = 0; ky < 3; ++ky)
#pragma unroll
            for (int kx = 0; kx < 3; ++kx) {
                int y = h + ky - 1, x = w + kx - 1;
                bool ok = (y >= 0) && (y < 128) && (x >= 0) && (x < 128);
                v[ky * 3 + kx] = ok ? f[y * 128 + x] : 0.0f;
            }
#pragma unroll
        for (int kk = 0; kk < 9; ++kk) {
            const float* wr = offT + ((c0 + i) * 9 + kk) * 28;
#pragma unroll
            for (int o = 0; o < 27; ++o) acc[o] = fmaf(v[kk], wr[o], acc[o]);
        }
    }

#pragma unroll
    for (int o = 0; o < 27; ++o) po[(wv * 27 + o) * 64 + lane] = acc[o];
    __syncthreads();

#pragma unroll
    for (int j = 0; j < 7; ++j) {
        int o = wv + 4 * j;
        if (o < 27) {
            float s = off_b[o]
                    + po[o * 64 + lane] + po[(27 + o) * 64 + lane]
                    + po[(54 + o) * 64 + lane] + po[(81 + o) * 64 + lane];
            oo[((b * 27 + o) << 14) + q] = s;
        }
    }
}

// ---------------------------------------------------------------------------
// Kernel 2.5: overwrite d_out (which held featN) with the dcn bias --
// runs after off has consumed featN; dcn halves then atomicAdd partials.
// ---------------------------------------------------------------------------
__global__ __launch_bounds__(256) void init_out_kernel(
    const float* __restrict__ dcn_b, float* __restrict__ out4)
{
    int idx = blockIdx.x * 256 + threadIdx.x;   // float4 index, 1M total
    int o = (idx >> 12) & 63;                   // (idx*4)>>14
    float bv = dcn_b[o];
    ((float4*)out4)[idx] = make_float4(bv, bv, bv, bv);
}

// ---------------------------------------------------------------------------
// Kernel 3: transform + deformable sampling + einsum (k-SPLIT).
// 2048 blocks: gid<1024 -> k=0..3, gid>=1024 -> k=4..8 (same pixel tile via
// bid=gid&1023; gid%8==bid%8 keeps both halves on one XCD). Single 16 KB
// sample buffer, 2 barriers/k (loads issued BEFORE barrier 1 so latency
// hides under the wait). 8 blocks/CU = 32 waves/CU. Partials atomicAdd'd
// into bias-initialized out.
// ---------------------------------------------------------------------------
__device__ __forceinline__ void dcn_transform_r(
    float oy, float ox, float mlraw, int k, int h, int w,
    float& W00, float& W01, float& W10, float& W11,
    int& i00, int& i01, int& i10, int& i11)
{
    float ml = 1.0f / (1.0f + expf(-mlraw));
    float py = (float)(h + k / 3 - 1) + oy;
    float px = (float)(w + k % 3 - 1) + ox;

    float y0f = floorf(py), x0f = floorf(px);
    float ly = py - y0f, lx = px - x0f;
    int y0 = (int)y0f, x0 = (int)x0f;

    bool vy0 = (y0f >= 0.0f)        && (y0f <= 127.0f);
    bool vy1 = (y0f + 1.0f >= 0.0f) && (y0f + 1.0f <= 127.0f);
    bool vx0 = (x0f >= 0.0f)        && (x0f <= 127.0f);
    bool vx1 = (x0f + 1.0f >= 0.0f) && (x0f + 1.0f <= 127.0f);

    int yc0 = min(max(y0, 0), 127),     yc1 = min(max(y0 + 1, 0), 127);
    int xc0 = min(max(x0, 0), 127),     xc1 = min(max(x0 + 1, 0), 127);

    W00 = (1.0f - ly) * (1.0f - lx) * ml * ((vy0 && vx0) ? 1.0f : 0.0f);
    W01 = (1.0f - ly) * lx          * ml * ((vy0 && vx1) ? 1.0f : 0.0f);
    W10 = ly * (1.0f - lx)          * ml * ((vy1 && vx0) ? 1.0f : 0.0f);
    W11 = ly * lx                   * ml * ((vy1 && vx1) ? 1.0f : 0.0f);

    i00 = yc0 * 128 + xc0; i01 = yc0 * 128 + xc1;
    i10 = yc1 * 128 + xc0; i11 = yc1 * 128 + xc1;
}

__global__ __launch_bounds__(256) void dcn_kernel(
    const float* __restrict__ feat2,
    const float* __restrict__ oo,
    const float* __restrict__ dcnT,
    float* __restrict__ out)
{
    __shared__ float s[64 * 64];   // single 16 KB sample buffer [ic][px]
    int tid  = threadIdx.x;
    int wv   = __builtin_amdgcn_readfirstlane(tid >> 6);
    int lane = tid & 63;
    int gid  = blockIdx.x;
    int half = gid >> 10;
    int bid  = gid & 1023;
    int p = swz_block(bid) * 64 + lane;
    int b = p >> 14;
    int q = p & 16383;
    int h = q >> 7;
    int w = q & 127;
    int c0 = wv * 16;
    int k0 = half ? 4 : 0;
    int k1 = half ? 9 : 4;

    float acc[16];
#pragma unroll
    for (int j = 0; j < 16; ++j) acc[j] = 0.0f;   // bias pre-filled by init_out

    const float* fb2 = feat2 + (size_t)(b * 16384) * 64 + c0;  // wave's ic slice
    const float* oob = oo + ((b * 27) << 14) + q;

    // prefetch oo for k0
    float oyN = oob[(2 * k0) << 14];
    float oxN = oob[(2 * k0 + 1) << 14];
    float omN = oob[(18 + k0) << 14];

    for (int k = k0; k < k1; ++k) {
        float W00, W01, W10, W11; int i00, i01, i10, i11;
        dcn_transform_r(oyN, oxN, omN, k, h, w, W00, W01, W10, W11,
                        i00, i01, i10, i11);
        if (k + 1 < k1) {   // prefetch next k's oo
            oyN = oob[(2 * (k + 1)) << 14];
            oxN = oob[(2 * (k + 1) + 1) << 14];
            omN = oob[(18 + (k + 1)) << 14];
        }

        // gather + blend own 16-ic slice (4 float4/corner; max 4 live float4)
        const float4* p00 = (const float4*)(fb2 + i00 * 64);
        const float4* p01 = (const float4*)(fb2 + i01 * 64);
        const float4* p10 = (const float4*)(fb2 + i10 * 64);
        const float4* p11 = (const float4*)(fb2 + i11 * 64);
        float sv[16];
#pragma unroll
        for (int g = 0; g < 4; ++g) {
            float4 a = p00[g], bb = p01[g], cc = p10[g], dd = p11[g];
            sv[4 * g + 0] = W00 * a.x + W01 * bb.x + W10 * cc.x + W11 * dd.x;
            sv[4 * g + 1] = W00 * a.y + W01 * bb.y + W10 * cc.y + W11 * dd.y;
            sv[4 * g + 2] = W00 * a.z + W01 * bb.z + W10 * cc.z + W11 * dd.z;
            sv[4 * g + 3] = W00 * a.w + W01 * bb.w + W10 * cc.w + W11 * dd.w;
        }

        __syncthreads();   // previous FMA phase done -> safe to overwrite s
#pragma unroll
        for (int j = 0; j < 16; ++j) s[(c0 + j) * 64 + lane] = sv[j];
        __syncthreads();   // samples ready

        const float* wk = dcnT + (size_t)k * 4096 + c0;
#pragma unroll 8
        for (int ic = 0; ic < 64; ++ic) {
            float sample = s[ic * 64 + lane];
            const float* wr = wk + ic * 64;
#pragma unroll
            for (int j = 0; j < 16; ++j) acc[j] = fmaf(sample, wr[j], acc[j]);
        }
    }

    float* ob = out + (b * 64 + c0) * 16384 + q;
#pragma unroll
    for (int j = 0; j < 16; ++j) atomicAdd(&ob[j * 16384], acc[j]);
}

// ---------------------------------------------------------------------------
extern "C" void kernel_launch(void* const* d_in, const int* in_sizes, int n_in,
                              void* d_out, int out_size, void* d_ws, size_t ws_size,
                              hipStream_t stream)
{
    const float* ev    = (const float*)d_in[0];
    const float* im    = (const float*)d_in[1];
    const float* w0    = (const float*)d_in[2];
    const float* b0    = (const float*)d_in[3];
    const float* w1    = (const float*)d_in[4];
    const float* b1    = (const float*)d_in[5];
    const float* w2    = (const float*)d_in[6];
    const float* b2    = (const float*)d_in[7];
    const float* w3    = (const float*)d_in[8];
    const float* b3    = (const float*)d_in[9];
    const float* off_w = (const float*)d_in[10];
    const float* off_b = (const float*)d_in[11];
    const float* dcn_w = (const float*)d_in[12];
    const float* dcn_b = (const float*)d_in[13];
    float* out = (float*)d_out;

    char* ws = (char*)d_ws;
    float* feat2 = (float*)(ws);                       // 16,777,216 B (NHWC)
    float* oo    = (float*)(ws + 16777216);            //  7,077,888 B
    float* offT  = (float*)(ws + 23855104);            //     64,512 B
    float* dcnT  = (float*)(ws + 23920640);            //    147,456 B
    float* featN = out;   // NCHW copy aliased into d_out (dead after off)

    mlp_kernel<<<NWG, 256, 0, stream>>>(ev, im, w0, b0, w1, b1, w2, b2,
                                        w3, b3, off_w, dcn_w, offT, dcnT,
                                        feat2, featN);
    off_kernel<<<NWG, 256, 0, stream>>>(featN, offT, off_b, oo);
    init_out_kernel<<<4096, 256, 0, stream>>>(dcn_b, out);
    dcn_kernel<<<2 * NWG, 256, 0, stream>>>(feat2, oo, dcnT, out);
}

// Round 19
// 158.915 us; speedup vs baseline: 2.2469x; 1.1823x over previous
//
#include <hip/hip_runtime.h>
#include <math.h>

// Problem constants
#define CCH 64
#define HH  128
#define WW  128
#define NB  4
#define NPIX (NB*HH*WW)   // 65536
#define NWG  (NPIX/64)    // 1024 blocks for the pixel kernels

// XCD-aware block swizzle (T1): each XCD gets a contiguous 64-row slice.
__device__ __forceinline__ int swz_block(int bid) {
    return (bid & 7) * (NWG >> 3) + (bid >> 3);
}

// ---------------------------------------------------------------------------
// Kernel 1: prep (first 144 blocks) + fused 4-layer MLP -> feat2 (NHWC) and
// featN (NCHW aliased into d_out; dead until dcn's final write).
// ---------------------------------------------------------------------------
__global__ __launch_bounds__(256) void mlp_kernel(
    const float* __restrict__ ev, const float* __restrict__ im,
    const float* __restrict__ w0, const float* __restrict__ b0,
    const float* __restrict__ w1, const float* __restrict__ b1,
    const float* __restrict__ w2, const float* __restrict__ b2,
    const float* __restrict__ w3, const float* __restrict__ b3,
    const float* __restrict__ off_w, const float* __restrict__ dcn_w,
    float* __restrict__ offT, float* __restrict__ dcnT,
    float* __restrict__ feat2, float* __restrict__ featN)
{
    __shared__ float xA[64 * 65];   // [ch][px], padded
    __shared__ float xB[64 * 65];
    int tid  = threadIdx.x;

    // folded prep: transpose conv weights (blocks 0..143)
    if (blockIdx.x < 144) {
        int idx = blockIdx.x * 256 + tid;
        if (idx < 576 * 28) {
            int rc = idx / 28;       // ic*9+kk
            int o  = idx % 28;
            offT[rc * 28 + o] = (o < 27) ? off_w[o * 576 + rc] : 0.0f;
        }
        if (idx < 36864) {
            int o    = idx & 63;
            int rest = idx >> 6;
            int ic   = rest & 63;
            int k    = rest >> 6;
            dcnT[(k * 64 + ic) * 64 + o] = dcn_w[o * 576 + ic * 9 + k];
        }
    }

    int cg   = __builtin_amdgcn_readfirstlane(tid >> 6);
    int lane = tid & 63;
    int sw   = swz_block(blockIdx.x);
    int p = sw * 64 + lane;
    int b = p >> 14;
    int q = p & 16383;
    int h = q >> 7;
    int w = q & 127;
    int c0 = cg * 16;

    float acc[16];
#pragma unroll
    for (int j = 0; j < 16; ++j) acc[j] = b0[c0 + j];

    const float* evb = ev + ((b * 64) * 64 + (h >> 1)) * 64 + (w >> 1);
    for (int i = 0; i < 64; ++i) {
        float v = evb[i * 4096];
        const float* wr = w0 + i * 64 + c0;
#pragma unroll
        for (int j = 0; j < 16; ++j) acc[j] = fmaf(v, wr[j], acc[j]);
    }
    const float* imb = im + ((b * 64) * 128 + h) * 128 + w;
    for (int i = 0; i < 64; ++i) {
        float v = imb[i * 16384];
        const float* wr = w0 + (64 + i) * 64 + c0;
#pragma unroll
        for (int j = 0; j < 16; ++j) acc[j] = fmaf(v, wr[j], acc[j]);
    }
    {
        float rely = (h & 1) ? 0.5f : -0.5f;
        float relx = (w & 1) ? 0.5f : -0.5f;
        const float* wr = w0 + 128 * 64 + c0;
#pragma unroll
        for (int j = 0; j < 16; ++j) acc[j] = fmaf(rely, wr[j], acc[j]);
#pragma unroll
        for (int j = 0; j < 16; ++j) acc[j] = fmaf(relx, wr[64 + j], acc[j]);
#pragma unroll
        for (int j = 0; j < 16; ++j) acc[j] += wr[128 + j] + wr[192 + j];
    }
#pragma unroll
    for (int j = 0; j < 16; ++j) xA[(c0 + j) * 65 + lane] = fmaxf(acc[j], 0.0f);
    __syncthreads();

#pragma unroll
    for (int j = 0; j < 16; ++j) acc[j] = b1[c0 + j];
    for (int i = 0; i < 64; ++i) {
        float v = xA[i * 65 + lane];
        const float* wr = w1 + i * 64 + c0;
#pragma unroll
        for (int j = 0; j < 16; ++j) acc[j] = fmaf(v, wr[j], acc[j]);
    }
#pragma unroll
    for (int j = 0; j < 16; ++j) xB[(c0 + j) * 65 + lane] = fmaxf(acc[j], 0.0f);
    __syncthreads();

#pragma unroll
    for (int j = 0; j < 16; ++j) acc[j] = b2[c0 + j];
    for (int i = 0; i < 64; ++i) {
        float v = xB[i * 65 + lane];
        const float* wr = w2 + i * 64 + c0;
#pragma unroll
        for (int j = 0; j < 16; ++j) acc[j] = fmaf(v, wr[j], acc[j]);
    }
#pragma unroll
    for (int j = 0; j < 16; ++j) xA[(c0 + j) * 65 + lane] = fmaxf(acc[j], 0.0f);
    __syncthreads();

#pragma unroll
    for (int j = 0; j < 16; ++j) acc[j] = b3[c0 + j];
    for (int i = 0; i < 64; ++i) {
        float v = xA[i * 65 + lane];
        const float* wr = w3 + i * 64 + c0;
#pragma unroll
        for (int j = 0; j < 16; ++j) acc[j] = fmaf(v, wr[j], acc[j]);
    }

    // NCHW store (coalesced: lanes = consecutive px)
    float* fbN = featN + (b * 64 + c0) * 16384 + q;
#pragma unroll
    for (int j = 0; j < 16; ++j) fbN[j * 16384] = acc[j];

    // NHWC store via padded-LDS transpose (coalesced float4)
#pragma unroll
    for (int j = 0; j < 16; ++j) xB[(c0 + j) * 65 + lane] = acc[j];
    __syncthreads();
    {
        int q0 = (sw * 64) & 16383;
        float* fb = feat2 + ((size_t)b * 16384 + q0) * 64;
        int ch0 = (tid & 15) * 4;
#pragma unroll
        for (int r = 0; r < 4; ++r) {
            int px = (tid >> 4) + r * 16;
            float4 v = make_float4(xB[(ch0 + 0) * 65 + px],
                                   xB[(ch0 + 1) * 65 + px],
                                   xB[(ch0 + 2) * 65 + px],
                                   xB[(ch0 + 3) * 65 + px]);
            ((float4*)fb)[tid + r * 256] = v;
        }
    }
}

// ---------------------------------------------------------------------------
// Kernel 2: 3x3 offset conv -> raw 27-ch oo.  NCHW reads (featN in d_out).
// ---------------------------------------------------------------------------
__global__ __launch_bounds__(256) void off_kernel(
    const float* __restrict__ featN, const float* __restrict__ offT,
    const float* __restrict__ off_b,
    float* __restrict__ oo)
{
    __shared__ float po[4 * 27 * 64];   // [wave][o][px]
    int tid  = threadIdx.x;
    int wv   = __builtin_amdgcn_readfirstlane(tid >> 6);
    int lane = tid & 63;
    int p = swz_block(blockIdx.x) * 64 + lane;
    int b = p >> 14;
    int q = p & 16383;
    int h = q >> 7;
    int w = q & 127;
    int c0 = wv * 16;

    float acc[27];
#pragma unroll
    for (int o = 0; o < 27; ++o) acc[o] = 0.0f;

    const float* fb = featN + (b * 64 + c0) * 16384;
    for (int i = 0; i < 16; ++i) {
        const float* f = fb + i * 16384;
        float v[9];
#pragma unroll
        for (int ky = 0; ky < 3; ++ky)
#pragma unroll
            for (int kx = 0; kx < 3; ++kx) {
                int y = h + ky - 1, x = w + kx - 1;
                bool ok = (y >= 0) && (y < 128) && (x >= 0) && (x < 128);
                v[ky * 3 + kx] = ok ? f[y * 128 + x] : 0.0f;
            }
#pragma unroll
        for (int kk = 0; kk < 9; ++kk) {
            const float* wr = offT + ((c0 + i) * 9 + kk) * 28;
#pragma unroll
            for (int o = 0; o < 27; ++o) acc[o] = fmaf(v[kk], wr[o], acc[o]);
        }
    }

#pragma unroll
    for (int o = 0; o < 27; ++o) po[(wv * 27 + o) * 64 + lane] = acc[o];
    __syncthreads();

#pragma unroll
    for (int j = 0; j < 7; ++j) {
        int o = wv + 4 * j;
        if (o < 27) {
            float s = off_b[o]
                    + po[o * 64 + lane] + po[(27 + o) * 64 + lane]
                    + po[(54 + o) * 64 + lane] + po[(81 + o) * 64 + lane];
            oo[((b * 27 + o) << 14) + q] = s;
        }
    }
}

// ---------------------------------------------------------------------------
// Kernel 3: transform + deformable sampling + einsum + bias.
// r9/r11 proven structure (ds_read_b32 samples + SGPR weight rows) with
// oo values prefetched 2 iterations ahead into registers (r14).
// ---------------------------------------------------------------------------
__device__ __forceinline__ void dcn_transform_r(
    float oy, float ox, float mlraw, int k, int h, int w,
    float& W00, float& W01, float& W10, float& W11,
    int& i00, int& i01, int& i10, int& i11)
{
    float ml = 1.0f / (1.0f + expf(-mlraw));
    float py = (float)(h + k / 3 - 1) + oy;
    float px = (float)(w + k % 3 - 1) + ox;

    float y0f = floorf(py), x0f = floorf(px);
    float ly = py - y0f, lx = px - x0f;
    int y0 = (int)y0f, x0 = (int)x0f;

    bool vy0 = (y0f >= 0.0f)        && (y0f <= 127.0f);
    bool vy1 = (y0f + 1.0f >= 0.0f) && (y0f + 1.0f <= 127.0f);
    bool vx0 = (x0f >= 0.0f)        && (x0f <= 127.0f);
    bool vx1 = (x0f + 1.0f >= 0.0f) && (x0f + 1.0f <= 127.0f);

    int yc0 = min(max(y0, 0), 127),     yc1 = min(max(y0 + 1, 0), 127);
    int xc0 = min(max(x0, 0), 127),     xc1 = min(max(x0 + 1, 0), 127);

    W00 = (1.0f - ly) * (1.0f - lx) * ml * ((vy0 && vx0) ? 1.0f : 0.0f);
    W01 = (1.0f - ly) * lx          * ml * ((vy0 && vx1) ? 1.0f : 0.0f);
    W10 = ly * (1.0f - lx)          * ml * ((vy1 && vx0) ? 1.0f : 0.0f);
    W11 = ly * lx                   * ml * ((vy1 && vx1) ? 1.0f : 0.0f);

    i00 = yc0 * 128 + xc0; i01 = yc0 * 128 + xc1;
    i10 = yc1 * 128 + xc0; i11 = yc1 * 128 + xc1;
}

__global__ __launch_bounds__(256) void dcn_kernel(
    const float* __restrict__ feat2,
    const float* __restrict__ oo,
    const float* __restrict__ dcnT, const float* __restrict__ dcn_b,
    float* __restrict__ out)
{
    __shared__ float sA[64 * 64];   // [ic][px]
    __shared__ float sB[64 * 64];
    int tid  = threadIdx.x;
    int wv   = __builtin_amdgcn_readfirstlane(tid >> 6);
    int lane = tid & 63;
    int p = swz_block(blockIdx.x) * 64 + lane;
    int b = p >> 14;
    int q = p & 16383;
    int h = q >> 7;
    int w = q & 127;
    int c0 = wv * 16;

    float acc[16];
#pragma unroll
    for (int j = 0; j < 16; ++j) acc[j] = dcn_b[c0 + j];

    const float* fb2 = feat2 + (b * 16384) * 64 + c0;   // wave's 16-ic slice
    const float* oob = oo + ((b * 27) << 14) + q;

    // ---- prologue: k=0 transform+gather into sA; prefetch k=1 oo ----
    {
        float oy = oob[0];
        float ox = oob[1 << 14];
        float om = oob[18 << 14];
        float W00, W01, W10, W11; int i00, i01, i10, i11;
        dcn_transform_r(oy, ox, om, 0, h, w, W00, W01, W10, W11, i00, i01, i10, i11);
        const float4* p00 = (const float4*)(fb2 + i00 * 64);
        const float4* p01 = (const float4*)(fb2 + i01 * 64);
        const float4* p10 = (const float4*)(fb2 + i10 * 64);
        const float4* p11 = (const float4*)(fb2 + i11 * 64);
#pragma unroll
        for (int g = 0; g < 4; ++g) {
            float4 a = p00[g], bb = p01[g], c = p10[g], d = p11[g];
            sA[(c0 + 4 * g + 0) * 64 + lane] = W00 * a.x + W01 * bb.x + W10 * c.x + W11 * d.x;
            sA[(c0 + 4 * g + 1) * 64 + lane] = W00 * a.y + W01 * bb.y + W10 * c.y + W11 * d.y;
            sA[(c0 + 4 * g + 2) * 64 + lane] = W00 * a.z + W01 * bb.z + W10 * c.z + W11 * d.z;
            sA[(c0 + 4 * g + 3) * 64 + lane] = W00 * a.w + W01 * bb.w + W10 * c.w + W11 * d.w;
        }
    }
    float oyN = oob[2 << 14];
    float oxN = oob[3 << 14];
    float omN = oob[19 << 14];
    __syncthreads();

    float* cur = sA;
    float* nxt = sB;

    for (int k = 0; k < 9; ++k) {
        bool pre = (k < 8);
        float W00, W01, W10, W11; int i00, i01, i10, i11;
        float4 a0, a1, b0, b1, c0v, c1v, d0, d1;
        const float4 *p00 = nullptr, *p01 = nullptr, *p10 = nullptr, *p11 = nullptr;

        if (pre) {
            // transform for k+1 from prefetched regs (pure VALU, no mem dep)
            dcn_transform_r(oyN, oxN, omN, k + 1, h, w,
                            W00, W01, W10, W11, i00, i01, i10, i11);
            // prefetch oo for k+2
            if (k < 7) {
                oyN = oob[(2 * (k + 2)) << 14];
                oxN = oob[(2 * (k + 2) + 1) << 14];
                omN = oob[(18 + (k + 2)) << 14];
            }
            p00 = (const float4*)(fb2 + i00 * 64);
            p01 = (const float4*)(fb2 + i01 * 64);
            p10 = (const float4*)(fb2 + i10 * 64);
            p11 = (const float4*)(fb2 + i11 * 64);
            a0 = p00[0]; a1 = p00[1];
            b0 = p01[0]; b1 = p01[1];
            c0v = p10[0]; c1v = p10[1];
            d0 = p11[0]; d1 = p11[1];
        }

        const float* wk = dcnT + (k * 64) * 64 + c0;
        // FMA half-phase 1: ic 0..31
#pragma unroll 8
        for (int ic = 0; ic < 32; ++ic) {
            float s = cur[ic * 64 + lane];
            const float* wr = wk + ic * 64;
#pragma unroll
            for (int j = 0; j < 16; ++j) acc[j] = fmaf(s, wr[j], acc[j]);
        }

        if (pre) {
            nxt[(c0 + 0) * 64 + lane] = W00 * a0.x + W01 * b0.x + W10 * c0v.x + W11 * d0.x;
            nxt[(c0 + 1) * 64 + lane] = W00 * a0.y + W01 * b0.y + W10 * c0v.y + W11 * d0.y;
            nxt[(c0 + 2) * 64 + lane] = W00 * a0.z + W01 * b0.z + W10 * c0v.z + W11 * d0.z;
            nxt[(c0 + 3) * 64 + lane] = W00 * a0.w + W01 * b0.w + W10 * c0v.w + W11 * d0.w;
            nxt[(c0 + 4) * 64 + lane] = W00 * a1.x + W01 * b1.x + W10 * c1v.x + W11 * d1.x;
            nxt[(c0 + 5) * 64 + lane] = W00 * a1.y + W01 * b1.y + W10 * c1v.y + W11 * d1.y;
            nxt[(c0 + 6) * 64 + lane] = W00 * a1.z + W01 * b1.z + W10 * c1v.z + W11 * d1.z;
            nxt[(c0 + 7) * 64 + lane] = W00 * a1.w + W01 * b1.w + W10 * c1v.w + W11 * d1.w;
            a0 = p00[2]; a1 = p00[3];
            b0 = p01[2]; b1 = p01[3];
            c0v = p10[2]; c1v = p10[3];
            d0 = p11[2]; d1 = p11[3];
        }

        // FMA half-phase 2: ic 32..63
#pragma unroll 8
        for (int ic = 32; ic < 64; ++ic) {
            float s = cur[ic * 64 + lane];
            const float* wr = wk + ic * 64;
#pragma unroll
            for (int j = 0; j < 16; ++j) acc[j] = fmaf(s, wr[j], acc[j]);
        }

        if (pre) {
            nxt[(c0 +  8) * 64 + lane] = W00 * a0.x + W01 * b0.x + W10 * c0v.x + W11 * d0.x;
            nxt[(c0 +  9) * 64 + lane] = W00 * a0.y + W01 * b0.y + W10 * c0v.y + W11 * d0.y;
            nxt[(c0 + 10) * 64 + lane] = W00 * a0.z + W01 * b0.z + W10 * c0v.z + W11 * d0.z;
            nxt[(c0 + 11) * 64 + lane] = W00 * a0.w + W01 * b0.w + W10 * c0v.w + W11 * d0.w;
            nxt[(c0 + 12) * 64 + lane] = W00 * a1.x + W01 * b1.x + W10 * c1v.x + W11 * d1.x;
            nxt[(c0 + 13) * 64 + lane] = W00 * a1.y + W01 * b1.y + W10 * c1v.y + W11 * d1.y;
            nxt[(c0 + 14) * 64 + lane] = W00 * a1.z + W01 * b1.z + W10 * c1v.z + W11 * d1.z;
            nxt[(c0 + 15) * 64 + lane] = W00 * a1.w + W01 * b1.w + W10 * c1v.w + W11 * d1.w;
        }

        __syncthreads();
        float* t = cur; cur = nxt; nxt = t;
    }

    float* ob = out + (b * 64 + c0) * 16384 + q;
#pragma unroll
    for (int j = 0; j < 16; ++j) ob[j * 16384] = acc[j];
}

// ---------------------------------------------------------------------------
extern "C" void kernel_launch(void* const* d_in, const int* in_sizes, int n_in,
                              void* d_out, int out_size, void* d_ws, size_t ws_size,
                              hipStream_t stream)
{
    const float* ev    = (const float*)d_in[0];
    const float* im    = (const float*)d_in[1];
    const float* w0    = (const float*)d_in[2];
    const float* b0    = (const float*)d_in[3];
    const float* w1    = (const float*)d_in[4];
    const float* b1    = (const float*)d_in[5];
    const float* w2    = (const float*)d_in[6];
    const float* b2    = (const float*)d_in[7];
    const float* w3    = (const float*)d_in[8];
    const float* b3    = (const float*)d_in[9];
    const float* off_w = (const float*)d_in[10];
    const float* off_b = (const float*)d_in[11];
    const float* dcn_w = (const float*)d_in[12];
    const float* dcn_b = (const float*)d_in[13];
    float* out = (float*)d_out;

    char* ws = (char*)d_ws;
    float* feat2 = (float*)(ws);                       // 16,777,216 B (NHWC)
    float* oo    = (float*)(ws + 16777216);            //  7,077,888 B
    float* offT  = (float*)(ws + 23855104);            //     64,512 B
    float* dcnT  = (float*)(ws + 23920640);            //    147,456 B
    float* featN = out;   // NCHW copy aliased into d_out (dead before dcn's write)

    mlp_kernel<<<NWG, 256, 0, stream>>>(ev, im, w0, b0, w1, b1, w2, b2,
                                        w3, b3, off_w, dcn_w, offT, dcnT,
                                        feat2, featN);
    off_kernel<<<NWG, 256, 0, stream>>>(featN, offT, off_b, oo);
    dcn_kernel<<<NWG, 256, 0, stream>>>(feat2, oo, dcnT, dcn_b, out);
}